// Round 6
// baseline (286.437 us; speedup 1.0000x reference)
//
#include <hip/hip_runtime.h>

// NeighConv: B=2, C=256, N=4096, K=16
// Pipeline (V matrix never materialized):
//  1) sq_kernel:     sq32[p], sq64[p] = ||x_p||^2
//  2) xt_kernel:     xt[p][c] fp32 + xh[p][c] fp16 (point-major features)
//  3) wt_kernel:     Wt[d][c] = W[c][d]
//  4) dist mode0:    LDS-staged MFMA gram (BK=32, 32KB LDS); per-query
//                    per-64col-tile minima
//  5) thresh:        T[q] = 20th smallest of 64 tile minima + 0.5 slack
//  6) dist mode1:    MFMA gram again; append all j with V <= T[q]
//  7) merge_rerank:  fp64 re-rank of survivors -> true top-16 + cosine weights
//  8) y_kernel:      Y1[p]=feat@W1^T, Y2[p]=feat@W2^T + b
//  9) final_kernel:  out[b][c][i] = max_k w_k*(Y1[nk][c]+Y2[m][c])

#define B_ 2
#define C_ 256
#define N_ 4096
#define K_ 16
#define SCAP 128
#define INF_F 3.0e38f

typedef _Float16 f16x8 __attribute__((ext_vector_type(8)));
typedef float    f32x4 __attribute__((ext_vector_type(4)));

// async global->LDS, 16B per lane; LDS dest wave-uniform base + lane*16
#define GL16(gp, lp)                                                        \
    __builtin_amdgcn_global_load_lds(                                       \
        (const __attribute__((address_space(1))) void*)(gp),                \
        (__attribute__((address_space(3))) void*)(lp), 16, 0, 0)

// ---------------- 1) squared norms ----------------
__global__ void sq_kernel(const float* __restrict__ x,
                          float* __restrict__ sq32, double* __restrict__ sq64) {
    int p = blockIdx.x * 256 + threadIdx.x;           // 0..8191
    int b = p >> 12, i = p & 4095;
    const float* xb = x + ((size_t)b << 20) + i;
    double acc = 0.0;
    #pragma unroll 8
    for (int c = 0; c < C_; ++c) {
        double v = (double)xb[(size_t)c << 12];
        acc = fma(v, v, acc);
    }
    sq64[p] = acc;
    sq32[p] = (float)acc;
}

// ---------------- 2) transpose x -> xt fp32 + xh fp16 ----------------
__global__ void xt_kernel(const float* __restrict__ x, float* __restrict__ xt,
                          _Float16* __restrict__ xh) {
    __shared__ float tile[64][65];
    int i0 = blockIdx.x * 64;
    int c0 = blockIdx.y * 64;
    int b  = blockIdx.z;
    const float* xb = x + ((size_t)b << 20);
    int tid = threadIdx.x;
    int tx = tid & 63, tyy = tid >> 6;
    for (int r = tyy; r < 64; r += 4)
        tile[r][tx] = xb[(size_t)(c0 + r) * N_ + i0 + tx];
    __syncthreads();
    float*    xtb = xt + ((size_t)b << 20);
    _Float16* xhb = xh + ((size_t)b << 20);
    for (int r = tyy; r < 64; r += 4) {
        float v = tile[tx][r];
        xtb[(size_t)(i0 + r) * C_ + c0 + tx] = v;
        xhb[(size_t)(i0 + r) * C_ + c0 + tx] = (_Float16)v;
    }
}

// ---------------- 3) transpose W -> Wt[d][c] ----------------
__global__ void wt_kernel(const float* __restrict__ W, float* __restrict__ Wt) {
    __shared__ float tile[64][65];
    int d0 = blockIdx.x * 64;
    int c0 = blockIdx.y * 64;
    int tid = threadIdx.x;
    int tx = tid & 63, tyy = tid >> 6;
    for (int r = tyy; r < 64; r += 4)
        tile[r][tx] = W[(size_t)(c0 + r) * 512 + d0 + tx];
    __syncthreads();
    for (int r = tyy; r < 64; r += 4)
        Wt[(size_t)(d0 + r) * C_ + c0 + tx] = tile[tx][r];
}

// ---------------- 4/6) LDS-staged MFMA distance kernel (no V store) ----------------
// block 256 = 4 waves (2x2 of 64x64), tile 128(i) x 128(j), BK=32 halfs.
// LDS 32KB total -> ~5 blocks/CU; TLP hides per-barrier staging latency.
// Swizzle (64B rows): logical byte cb of row r stored at cb ^ ((r&3)<<4).
// gload_lds writes linearly -> inverse swizzle applied to global SOURCE addr.
__launch_bounds__(256)
__global__ void dist_kernel(const _Float16* __restrict__ xh,
                            const float* __restrict__ sq32,
                            const float* __restrict__ Tq,
                            float* __restrict__ tmin,
                            int* __restrict__ svj, int* __restrict__ cntg,
                            int mode) {
    __shared__ _Float16 As[2][128][32];
    __shared__ _Float16 Bs[2][128][32];

    int jt = blockIdx.x, it = blockIdx.y, b = blockIdx.z;
    int tid = threadIdx.x;
    int w = tid >> 6, l = tid & 63;
    int wr = w >> 1, wc = w & 1;
    int lr = l & 15, lg = l >> 4;
    const _Float16* xb = xh + ((size_t)b << 20);
    int rA0 = it * 128, rB0 = jt * 128;

    // staging geometry: lane l covers row (l>>2) of its 16-row group,
    // byte (l&3)*16 within the 64B row
    int rsub = l >> 2;                          // 0..15
    int cb   = (l & 3) << 4;                    // 0..48 bytes

    auto STAGE = [&](int bf, int k0) {
        #pragma unroll
        for (int t = 0; t < 2; ++t) {
            int rloc = w * 32 + t * 16 + rsub;                 // 0..127
            int srch = (cb ^ ((rloc & 3) << 4)) >> 1;          // halfs
            GL16(xb + (size_t)(rA0 + rloc) * C_ + k0 + srch, &As[bf][w * 32 + t * 16][0]);
            GL16(xb + (size_t)(rB0 + rloc) * C_ + k0 + srch, &Bs[bf][w * 32 + t * 16][0]);
        }
    };

    f32x4 acc[4][4];
    #pragma unroll
    for (int mi = 0; mi < 4; ++mi)
        #pragma unroll
        for (int ni = 0; ni < 4; ++ni)
            acc[mi][ni] = (f32x4){0.f, 0.f, 0.f, 0.f};

    STAGE(0, 0);
    __syncthreads();                            // drains vmcnt -> buf0 ready
    #pragma unroll
    for (int kt = 0; kt < 8; ++kt) {
        int cur = kt & 1;
        if (kt < 7) STAGE(cur ^ 1, (kt + 1) * 32);
        int kh = lg * 8;                        // halfs offset within BK=32
        f16x8 af[4], bf4[4];
        #pragma unroll
        for (int mi = 0; mi < 4; ++mi) {
            int r = wr * 64 + mi * 16 + lr;
            af[mi] = *(const f16x8*)&As[cur][r][kh ^ ((r & 3) << 3)];
        }
        #pragma unroll
        for (int ni = 0; ni < 4; ++ni) {
            int r = wc * 64 + ni * 16 + lr;
            bf4[ni] = *(const f16x8*)&Bs[cur][r][kh ^ ((r & 3) << 3)];
        }
        #pragma unroll
        for (int mi = 0; mi < 4; ++mi)
            #pragma unroll
            for (int ni = 0; ni < 4; ++ni)
                acc[mi][ni] = __builtin_amdgcn_mfma_f32_16x16x32_f16(
                    af[mi], bf4[ni], acc[mi][ni], 0, 0, 0);
        __syncthreads();                        // buf[cur^1] staged; buf[cur] free
    }

    int bN = b << 12;
    int irow0 = it * 128 + wr * 64 + lg * 4;    // + mi*16 + r

    if (mode == 0) {
        // per-query min over this wave's 64 cols
        float rm[4][4];
        #pragma unroll
        for (int mi = 0; mi < 4; ++mi)
            #pragma unroll
            for (int r = 0; r < 4; ++r) rm[mi][r] = INF_F;
        #pragma unroll
        for (int ni = 0; ni < 4; ++ni) {
            int jg = jt * 128 + wc * 64 + ni * 16 + lr;
            float sj = sq32[bN + jg];
            #pragma unroll
            for (int mi = 0; mi < 4; ++mi)
                #pragma unroll
                for (int r = 0; r < 4; ++r)
                    rm[mi][r] = fminf(rm[mi][r], sj - 2.0f * acc[mi][ni][r]);
        }
        #pragma unroll
        for (int mask = 1; mask <= 8; mask <<= 1)
            #pragma unroll
            for (int mi = 0; mi < 4; ++mi)
                #pragma unroll
                for (int r = 0; r < 4; ++r)
                    rm[mi][r] = fminf(rm[mi][r], __shfl_xor(rm[mi][r], mask));
        if (lr == 0) {
            int tj = jt * 2 + wc;
            #pragma unroll
            for (int mi = 0; mi < 4; ++mi)
                #pragma unroll
                for (int r = 0; r < 4; ++r)
                    tmin[(size_t)tj * 8192 + bN + irow0 + mi * 16 + r] = rm[mi][r];
        }
    } else {
        // filter-append survivors: V <= T[q] (T already has +0.5 slack)
        float tq[4][4];
        #pragma unroll
        for (int mi = 0; mi < 4; ++mi)
            #pragma unroll
            for (int r = 0; r < 4; ++r)
                tq[mi][r] = Tq[bN + irow0 + mi * 16 + r];
        #pragma unroll
        for (int ni = 0; ni < 4; ++ni) {
            int jg = jt * 128 + wc * 64 + ni * 16 + lr;
            float sj = sq32[bN + jg];
            #pragma unroll
            for (int mi = 0; mi < 4; ++mi)
                #pragma unroll
                for (int r = 0; r < 4; ++r) {
                    float v = sj - 2.0f * acc[mi][ni][r];
                    if (v <= tq[mi][r]) {
                        int q = bN + irow0 + mi * 16 + r;
                        int pos = atomicAdd(&cntg[q], 1);
                        if (pos < SCAP) svj[(size_t)q * SCAP + pos] = jg;
                    }
                }
        }
    }
}

// ---------------- 5) per-query threshold = 20th smallest tile-min ----------------
__global__ void thresh_kernel(const float* __restrict__ tmin, float* __restrict__ Tq) {
    int q = blockIdx.x * 256 + threadIdx.x;           // 0..8191
    float sm[20];
    #pragma unroll
    for (int s = 0; s < 20; ++s) sm[s] = INF_F;
    for (int tj = 0; tj < 64; ++tj) {
        float v = tmin[(size_t)tj * 8192 + q];
        #pragma unroll
        for (int s = 0; s < 20; ++s) {                // branchless sorted insert
            bool lt = v < sm[s];
            float old = sm[s];
            sm[s] = lt ? v : sm[s];
            v = lt ? old : v;
        }
    }
    Tq[q] = sm[19] + 0.5f;
}

// ---------------- 7) fp64 re-rank of survivors + weights ----------------
__global__ void merge_rerank(const int* __restrict__ svj, const int* __restrict__ cntg,
                             const float* __restrict__ xt,
                             const double* __restrict__ sq64,
                             int* __restrict__ nidx, float* __restrict__ wgt) {
    __shared__ double d64[32][SCAP];
    int tid = threadIdx.x;
    int pl = tid >> 3, c8 = tid & 7;
    int m = (blockIdx.x << 5) + pl;
    int b = m >> 12;
    int cnt = cntg[m]; if (cnt > SCAP) cnt = SCAP;
    const float* rm = xt + ((size_t)m << 8);
    for (int cc = c8; cc < cnt; cc += 8) {
        int j = svj[(size_t)m * SCAP + cc];
        int n = (b << 12) + j;
        const float* rn = xt + ((size_t)n << 8);
        double acc = 0.0;
        #pragma unroll 8
        for (int c = 0; c < C_; c += 4) {
            float4 a4 = *(const float4*)(rm + c);
            float4 b4 = *(const float4*)(rn + c);
            acc = fma((double)a4.x, (double)b4.x, acc);
            acc = fma((double)a4.y, (double)b4.y, acc);
            acc = fma((double)a4.z, (double)b4.z, acc);
            acc = fma((double)a4.w, (double)b4.w, acc);
        }
        d64[pl][cc] = sq64[n] - 2.0 * acc;
    }
    __syncthreads();
    if (tid < 32) {
        int mm = (blockIdx.x << 5) + tid;
        int bb = mm >> 12;
        int cn = cntg[mm]; if (cn > SCAP) cn = SCAP;
        double td[K_]; int ti[K_];
        #pragma unroll
        for (int k = 0; k < K_; ++k) { td[k] = 1.0e300; ti[k] = 0; }
        for (int cc = 0; cc < cn; ++cc) {
            double d = d64[tid][cc];
            int j = svj[(size_t)mm * SCAP + cc];
            #pragma unroll
            for (int s = 0; s < K_; ++s) {            // sorted bubble-insert, strict <
                bool lt = d < td[s];
                double od = td[s]; int oi = ti[s];
                td[s] = lt ? d : od;  ti[s] = lt ? j : oi;
                d = lt ? od : d;      j = lt ? oi : j;
            }
        }
        double sqm = sq64[mm];
        double rdm = sqrt(sqm);
        #pragma unroll
        for (int k = 0; k < K_; ++k) {
            int n = (bb << 12) + ti[k];
            double sqn = sq64[n];
            double dot = 0.5 * (sqn - td[k]);
            double w = dot / (sqrt(sqn) * rdm);
            nidx[mm * K_ + k] = n;
            wgt[mm * K_ + k]  = (float)w;
        }
    }
}

// ---------------- 8) Y1 = feat@W1^T ; Y2 = feat@W2^T + b ----------------
#define YKC 32
__launch_bounds__(256, 2)
__global__ void y_kernel(const float* __restrict__ x, const float* __restrict__ Wt,
                         const float* __restrict__ bias,
                         float* __restrict__ Y1, float* __restrict__ Y2) {
    __shared__ float af[YKC][128];
    __shared__ float wf[YKC][128];
    int p0  = blockIdx.x << 7;
    int oc0 = blockIdx.y << 6;
    int b   = blockIdx.z;
    const float* xb = x + ((size_t)b << 20);
    int tid = threadIdx.x, tx = tid & 15, ty = tid >> 4;
    int tx4 = tx << 2, ty4 = ty << 2;
    float acc[8][8];
    #pragma unroll
    for (int a = 0; a < 8; ++a)
        #pragma unroll
        for (int b2 = 0; b2 < 8; ++b2) acc[a][b2] = 0.f;

    for (int cc0 = 0; cc0 < C_; cc0 += YKC) {
        __syncthreads();
        for (int e = tid; e < YKC * 128; e += 256) {
            int d = e >> 7, q = e & 127;
            af[d][q] = xb[(size_t)(cc0 + d) * N_ + p0 + q];
            int row = (q < 64) ? (cc0 + d) : (C_ + cc0 + d);
            wf[d][q] = Wt[(size_t)row * C_ + oc0 + (q & 63)];
        }
        __syncthreads();
        #pragma unroll 8
        for (int d = 0; d < YKC; ++d) {
            float4 a0 = *(const float4*)&af[d][ty4];
            float4 a1 = *(const float4*)&af[d][64 + ty4];
            float4 w0 = *(const float4*)&wf[d][tx4];
            float4 w1 = *(const float4*)&wf[d][64 + tx4];
            float pa[8] = {a0.x, a0.y, a0.z, a0.w, a1.x, a1.y, a1.z, a1.w};
            float wa[8] = {w0.x, w0.y, w0.z, w0.w, w1.x, w1.y, w1.z, w1.w};
            #pragma unroll
            for (int a = 0; a < 8; ++a)
                #pragma unroll
                for (int b2 = 0; b2 < 8; ++b2)
                    acc[a][b2] = fmaf(pa[a], wa[b2], acc[a][b2]);
        }
    }
    float4 bv = *(const float4*)&bias[oc0 + tx4];
    #pragma unroll
    for (int ha = 0; ha < 2; ++ha) {
        #pragma unroll
        for (int a = 0; a < 4; ++a) {
            int pg = (b << 12) + p0 + ha * 64 + ty4 + a;
            float4 o1, o2;
            o1.x = acc[ha * 4 + a][0]; o1.y = acc[ha * 4 + a][1];
            o1.z = acc[ha * 4 + a][2]; o1.w = acc[ha * 4 + a][3];
            o2.x = acc[ha * 4 + a][4] + bv.x; o2.y = acc[ha * 4 + a][5] + bv.y;
            o2.z = acc[ha * 4 + a][6] + bv.z; o2.w = acc[ha * 4 + a][7] + bv.w;
            *(float4*)&Y1[(size_t)pg * C_ + oc0 + tx4] = o1;
            *(float4*)&Y2[(size_t)pg * C_ + oc0 + tx4] = o2;
        }
    }
}

// ---------------- 9) weighted max epilogue ----------------
__global__ void final_kernel(const float* __restrict__ Y1, const float* __restrict__ Y2,
                             const int* __restrict__ nidx, const float* __restrict__ wgt,
                             float* __restrict__ out) {
    __shared__ int   snk[K_];
    __shared__ float swt[K_];
    int m = blockIdx.x;
    int c = threadIdx.x;
    if (c < K_) { snk[c] = nidx[m * K_ + c]; swt[c] = wgt[m * K_ + c]; }
    __syncthreads();
    float y2 = Y2[((size_t)m << 8) + c];
    float acc = -INF_F;
    #pragma unroll
    for (int k = 0; k < K_; ++k) {
        float v = swt[k] * (Y1[((size_t)snk[k] << 8) + c] + y2);
        acc = fmaxf(acc, v);
    }
    int b = m >> 12, i = m & 4095;
    out[(((size_t)b << 8) + c) * N_ + i] = acc;
}

extern "C" void kernel_launch(void* const* d_in, const int* in_sizes, int n_in,
                              void* d_out, int out_size, void* d_ws, size_t ws_size,
                              hipStream_t stream) {
    const float* x    = (const float*)d_in[0];
    const float* W    = (const float*)d_in[1];
    const float* bias = (const float*)d_in[2];
    float* out = (float*)d_out;

    float* ws = (float*)d_ws;
    size_t off = 0;
    float*  sq32 = ws + off;            off += 8192;
    double* sq64 = (double*)(ws + off); off += 16384;
    float*  Wt   = ws + off;            off += 131072;
    float*  wgt  = ws + off;            off += 131072;
    int*    nidx = (int*)(ws + off);    off += 131072;
    float*  Tq   = ws + off;            off += 8192;
    int*    cntg = (int*)(ws + off);    off += 8192;
    float*  tmin = ws + off;            off += 524288;     // 64 x 8192
    size_t svj_off = off;
    int*    svj  = (int*)(ws + off);    off += 1048576;    // 8192 x 128
    float*  xt   = ws + off;            off += 2097152;    // 2M floats
    size_t reuse0 = off;
    _Float16* xh = (_Float16*)(ws + reuse0);               // 2M halves
    // Y1/Y2 reuse svj+xt / xt-end+xh regions (dead after merge_rerank)
    float*  Y1   = ws + svj_off;
    float*  Y2   = Y1 + 2097152;

    hipMemsetAsync(cntg, 0, 8192 * sizeof(int), stream);
    sq_kernel<<<32, 256, 0, stream>>>(x, sq32, sq64);
    xt_kernel<<<dim3(64, 4, 2), 256, 0, stream>>>(x, xt, xh);
    wt_kernel<<<dim3(8, 4, 1), 256, 0, stream>>>(W, Wt);

    dist_kernel<<<dim3(32, 32, 2), 256, 0, stream>>>(xh, sq32, Tq, tmin, svj, cntg, 0);
    thresh_kernel<<<32, 256, 0, stream>>>(tmin, Tq);
    dist_kernel<<<dim3(32, 32, 2), 256, 0, stream>>>(xh, sq32, Tq, tmin, svj, cntg, 1);

    merge_rerank<<<256, 256, 0, stream>>>(svj, cntg, xt, sq64, nidx, wgt);
    y_kernel<<<dim3(32, 4, 2), 256, 0, stream>>>(x, Wt, bias, Y1, Y2);
    final_kernel<<<8192, 256, 0, stream>>>(Y1, Y2, nidx, wgt, out);
}

// Round 7
// 282.548 us; speedup vs baseline: 1.0138x; 1.0138x over previous
//
#include <hip/hip_runtime.h>

// NeighConv: B=2, C=256, N=4096, K=16
// Pipeline (V matrix never materialized):
//  1) sq_kernel:     sq32[p], sq64[p] = ||x_p||^2
//  2) xt_kernel:     xt[p][c] fp32 + xh[p][c] fp16 (point-major features)
//  3) wt_kernel:     Wt[d][c] = W[c][d]
//  4) dist mode0:    LDS-staged MFMA gram (BK=64, counted-vmcnt pipeline);
//                    per-query per-64col-tile minima
//  5) thresh:        T[q] = 20th smallest of 64 tile minima + 0.5 slack
//  6) dist mode1:    MFMA gram again; append all j with V <= T[q]
//  7) merge_rerank:  fp64 re-rank of survivors -> true top-16 + cosine weights
//  8) y_kernel:      Y1[p]=feat@W1^T, Y2[p]=feat@W2^T + b
//  9) final_kernel:  out[b][c][i] = max_k w_k*(Y1[nk][c]+Y2[m][c])

#define B_ 2
#define C_ 256
#define N_ 4096
#define K_ 16
#define SCAP 128
#define INF_F 3.0e38f

typedef _Float16 f16x8 __attribute__((ext_vector_type(8)));
typedef float    f32x4 __attribute__((ext_vector_type(4)));

// async global->LDS, 16B per lane; LDS dest wave-uniform base + lane*16
#define GL16(gp, lp)                                                        \
    __builtin_amdgcn_global_load_lds(                                       \
        (const __attribute__((address_space(1))) void*)(gp),                \
        (__attribute__((address_space(3))) void*)(lp), 16, 0, 0)

#define WAITV(n) asm volatile("s_waitcnt vmcnt(" #n ")" ::: "memory")
#define BAR()    __builtin_amdgcn_s_barrier()
#define SCHED0() __builtin_amdgcn_sched_barrier(0)

// ---------------- 1) squared norms ----------------
__global__ void sq_kernel(const float* __restrict__ x,
                          float* __restrict__ sq32, double* __restrict__ sq64) {
    int p = blockIdx.x * 256 + threadIdx.x;           // 0..8191
    int b = p >> 12, i = p & 4095;
    const float* xb = x + ((size_t)b << 20) + i;
    double acc = 0.0;
    #pragma unroll 8
    for (int c = 0; c < C_; ++c) {
        double v = (double)xb[(size_t)c << 12];
        acc = fma(v, v, acc);
    }
    sq64[p] = acc;
    sq32[p] = (float)acc;
}

// ---------------- 2) transpose x -> xt fp32 + xh fp16 ----------------
__global__ void xt_kernel(const float* __restrict__ x, float* __restrict__ xt,
                          _Float16* __restrict__ xh) {
    __shared__ float tile[64][65];
    int i0 = blockIdx.x * 64;
    int c0 = blockIdx.y * 64;
    int b  = blockIdx.z;
    const float* xb = x + ((size_t)b << 20);
    int tid = threadIdx.x;
    int tx = tid & 63, tyy = tid >> 6;
    for (int r = tyy; r < 64; r += 4)
        tile[r][tx] = xb[(size_t)(c0 + r) * N_ + i0 + tx];
    __syncthreads();
    float*    xtb = xt + ((size_t)b << 20);
    _Float16* xhb = xh + ((size_t)b << 20);
    for (int r = tyy; r < 64; r += 4) {
        float v = tile[tx][r];
        xtb[(size_t)(i0 + r) * C_ + c0 + tx] = v;
        xhb[(size_t)(i0 + r) * C_ + c0 + tx] = (_Float16)v;
    }
}

// ---------------- 3) transpose W -> Wt[d][c] ----------------
__global__ void wt_kernel(const float* __restrict__ W, float* __restrict__ Wt) {
    __shared__ float tile[64][65];
    int d0 = blockIdx.x * 64;
    int c0 = blockIdx.y * 64;
    int tid = threadIdx.x;
    int tx = tid & 63, tyy = tid >> 6;
    for (int r = tyy; r < 64; r += 4)
        tile[r][tx] = W[(size_t)(c0 + r) * 512 + d0 + tx];
    __syncthreads();
    for (int r = tyy; r < 64; r += 4)
        Wt[(size_t)(d0 + r) * C_ + c0 + tx] = tile[tx][r];
}

// ---------------- 4/6) pipelined MFMA distance kernel (no V store) ----------------
// block 256 = 4 waves (2x2 of 64x64), tile 128(i) x 128(j), BK=64 halfs.
// LDS XOR-swizzle (measured conflict-free): byte cb of row r at cb ^ ((r&7)<<4).
// gload_lds writes linearly -> inverse swizzle applied to global SOURCE addr.
// K-step phase: STAGE(next) -> vmcnt(8) -> barrier -> ds_read+MFMA -> barrier.
__launch_bounds__(256)
__global__ void dist_kernel(const _Float16* __restrict__ xh,
                            const float* __restrict__ sq32,
                            const float* __restrict__ Tq,
                            float* __restrict__ tmin,
                            int* __restrict__ svj, int* __restrict__ cntg,
                            int mode) {
    __shared__ _Float16 As[2][128][64];
    __shared__ _Float16 Bs[2][128][64];

    // bijective XCD-chunked remap: blocks sharing an A-panel share an XCD L2
    int flat = blockIdx.x + 32 * blockIdx.y + 1024 * blockIdx.z;   // 0..2047
    int nid  = (flat & 7) * 256 + (flat >> 3);
    int jt = nid & 31, it = (nid >> 5) & 31, b = nid >> 10;

    int tid = threadIdx.x;
    int w = tid >> 6, l = tid & 63;
    int wr = w >> 1, wc = w & 1;
    int lr = l & 15, lg = l >> 4;
    const _Float16* xb = xh + ((size_t)b << 20);
    int rA0 = it * 128, rB0 = jt * 128;
    int bN = b << 12;
    int irow0 = it * 128 + wr * 64 + lg * 4;    // + mi*16 + r

    // epilogue scalars loaded OUTSIDE the counted-vmcnt window (issued here,
    // retired by the first vmcnt(8); or sunk by compiler past the last vmcnt(0))
    float sj[2][4];
    #pragma unroll
    for (int ni = 0; ni < 4; ++ni) {
        sj[0][ni] = sq32[bN + jt * 128 + ni * 16 + lr];
        sj[1][ni] = sq32[bN + jt * 128 + 64 + ni * 16 + lr];
    }
    float tq[4][4];
    if (mode != 0) {
        #pragma unroll
        for (int mi = 0; mi < 4; ++mi)
            #pragma unroll
            for (int r = 0; r < 4; ++r)
                tq[mi][r] = Tq[bN + irow0 + mi * 16 + r];
    }

    // staging geometry: lane l covers row l>>3 of its 8-row group, byte (l&7)*16
    int rsub = l >> 3;                          // 0..7
    int cb   = (l & 7) << 4;                    // 0..112 bytes

    auto STAGE = [&](int bf, int k0) {          // 8 gl_lds instructions / wave
        #pragma unroll
        for (int t = 0; t < 4; ++t) {
            int rloc = w * 32 + t * 8 + rsub;                  // 0..127
            int srch = (cb ^ ((rloc & 7) << 4)) >> 1;          // halfs
            GL16(xb + (size_t)(rA0 + rloc) * C_ + k0 + srch, &As[bf][w * 32 + t * 8][0]);
            GL16(xb + (size_t)(rB0 + rloc) * C_ + k0 + srch, &Bs[bf][w * 32 + t * 8][0]);
        }
    };

    f32x4 acc[4][4];
    #pragma unroll
    for (int mi = 0; mi < 4; ++mi)
        #pragma unroll
        for (int ni = 0; ni < 4; ++ni)
            acc[mi][ni] = (f32x4){0.f, 0.f, 0.f, 0.f};

    STAGE(0, 0);
    #pragma unroll
    for (int kt = 0; kt < 4; ++kt) {
        int cur = kt & 1;
        if (kt < 3) {
            STAGE(cur ^ 1, (kt + 1) * 64);
            WAITV(8);                           // prev tile landed; next 8 in flight
        } else {
            WAITV(0);
        }
        BAR();                                  // buf[cur] ready for all waves
        SCHED0();                               // pin ds_reads below the barrier
        #pragma unroll
        for (int kk = 0; kk < 2; ++kk) {
            int kh = kk * 32 + lg * 8;          // halfs offset within BK
            f16x8 af[4], bf4[4];
            #pragma unroll
            for (int mi = 0; mi < 4; ++mi) {
                int r = wr * 64 + mi * 16 + lr;
                af[mi] = *(const f16x8*)&As[cur][r][kh ^ ((r & 7) << 3)];
            }
            #pragma unroll
            for (int ni = 0; ni < 4; ++ni) {
                int r = wc * 64 + ni * 16 + lr;
                bf4[ni] = *(const f16x8*)&Bs[cur][r][kh ^ ((r & 7) << 3)];
            }
            #pragma unroll
            for (int mi = 0; mi < 4; ++mi)
                #pragma unroll
                for (int ni = 0; ni < 4; ++ni)
                    acc[mi][ni] = __builtin_amdgcn_mfma_f32_16x16x32_f16(
                        af[mi], bf4[ni], acc[mi][ni], 0, 0, 0);
        }
        BAR();                                  // all reads of buf[cur] retired
    }

    if (mode == 0) {
        // per-query min over this wave's 64 cols
        float rm[4][4];
        #pragma unroll
        for (int mi = 0; mi < 4; ++mi)
            #pragma unroll
            for (int r = 0; r < 4; ++r) rm[mi][r] = INF_F;
        #pragma unroll
        for (int ni = 0; ni < 4; ++ni) {
            #pragma unroll
            for (int mi = 0; mi < 4; ++mi)
                #pragma unroll
                for (int r = 0; r < 4; ++r)
                    rm[mi][r] = fminf(rm[mi][r], sj[wc][ni] - 2.0f * acc[mi][ni][r]);
        }
        #pragma unroll
        for (int mask = 1; mask <= 8; mask <<= 1)
            #pragma unroll
            for (int mi = 0; mi < 4; ++mi)
                #pragma unroll
                for (int r = 0; r < 4; ++r)
                    rm[mi][r] = fminf(rm[mi][r], __shfl_xor(rm[mi][r], mask));
        if (lr == 0) {
            int tj = jt * 2 + wc;
            #pragma unroll
            for (int mi = 0; mi < 4; ++mi)
                #pragma unroll
                for (int r = 0; r < 4; ++r)
                    tmin[(size_t)tj * 8192 + bN + irow0 + mi * 16 + r] = rm[mi][r];
        }
    } else {
        // filter-append survivors: V <= T[q] (T already has +0.5 slack)
        #pragma unroll
        for (int ni = 0; ni < 4; ++ni) {
            int jg = jt * 128 + wc * 64 + ni * 16 + lr;
            #pragma unroll
            for (int mi = 0; mi < 4; ++mi)
                #pragma unroll
                for (int r = 0; r < 4; ++r) {
                    float v = sj[wc][ni] - 2.0f * acc[mi][ni][r];
                    if (v <= tq[mi][r]) {
                        int q = bN + irow0 + mi * 16 + r;
                        int pos = atomicAdd(&cntg[q], 1);
                        if (pos < SCAP) svj[(size_t)q * SCAP + pos] = jg;
                    }
                }
        }
    }
}

// ---------------- 5) per-query threshold = 20th smallest tile-min ----------------
__global__ void thresh_kernel(const float* __restrict__ tmin, float* __restrict__ Tq) {
    int q = blockIdx.x * 256 + threadIdx.x;           // 0..8191
    float sm[20];
    #pragma unroll
    for (int s = 0; s < 20; ++s) sm[s] = INF_F;
    for (int tj = 0; tj < 64; ++tj) {
        float v = tmin[(size_t)tj * 8192 + q];
        #pragma unroll
        for (int s = 0; s < 20; ++s) {                // branchless sorted insert
            bool lt = v < sm[s];
            float old = sm[s];
            sm[s] = lt ? v : sm[s];
            v = lt ? old : v;
        }
    }
    Tq[q] = sm[19] + 0.5f;
}

// ---------------- 7) fp64 re-rank of survivors + weights ----------------
__global__ void merge_rerank(const int* __restrict__ svj, const int* __restrict__ cntg,
                             const float* __restrict__ xt,
                             const double* __restrict__ sq64,
                             int* __restrict__ nidx, float* __restrict__ wgt) {
    __shared__ double d64[32][SCAP];
    int tid = threadIdx.x;
    int pl = tid >> 3, c8 = tid & 7;
    int m = (blockIdx.x << 5) + pl;
    int b = m >> 12;
    int cnt = cntg[m]; if (cnt > SCAP) cnt = SCAP;
    const float* rm = xt + ((size_t)m << 8);
    for (int cc = c8; cc < cnt; cc += 8) {
        int j = svj[(size_t)m * SCAP + cc];
        int n = (b << 12) + j;
        const float* rn = xt + ((size_t)n << 8);
        double acc = 0.0;
        #pragma unroll 8
        for (int c = 0; c < C_; c += 4) {
            float4 a4 = *(const float4*)(rm + c);
            float4 b4 = *(const float4*)(rn + c);
            acc = fma((double)a4.x, (double)b4.x, acc);
            acc = fma((double)a4.y, (double)b4.y, acc);
            acc = fma((double)a4.z, (double)b4.z, acc);
            acc = fma((double)a4.w, (double)b4.w, acc);
        }
        d64[pl][cc] = sq64[n] - 2.0 * acc;
    }
    __syncthreads();
    if (tid < 32) {
        int mm = (blockIdx.x << 5) + tid;
        int bb = mm >> 12;
        int cn = cntg[mm]; if (cn > SCAP) cn = SCAP;
        double td[K_]; int ti[K_];
        #pragma unroll
        for (int k = 0; k < K_; ++k) { td[k] = 1.0e300; ti[k] = 0; }
        for (int cc = 0; cc < cn; ++cc) {
            double d = d64[tid][cc];
            int j = svj[(size_t)mm * SCAP + cc];
            #pragma unroll
            for (int s = 0; s < K_; ++s) {            // sorted bubble-insert, strict <
                bool lt = d < td[s];
                double od = td[s]; int oi = ti[s];
                td[s] = lt ? d : od;  ti[s] = lt ? j : oi;
                d = lt ? od : d;      j = lt ? oi : j;
            }
        }
        double sqm = sq64[mm];
        double rdm = sqrt(sqm);
        #pragma unroll
        for (int k = 0; k < K_; ++k) {
            int n = (bb << 12) + ti[k];
            double sqn = sq64[n];
            double dot = 0.5 * (sqn - td[k]);
            double w = dot / (sqrt(sqn) * rdm);
            nidx[mm * K_ + k] = n;
            wgt[mm * K_ + k]  = (float)w;
        }
    }
}

// ---------------- 8) Y1 = feat@W1^T ; Y2 = feat@W2^T + b ----------------
#define YKC 32
__launch_bounds__(256, 2)
__global__ void y_kernel(const float* __restrict__ x, const float* __restrict__ Wt,
                         const float* __restrict__ bias,
                         float* __restrict__ Y1, float* __restrict__ Y2) {
    __shared__ float af[YKC][128];
    __shared__ float wf[YKC][128];
    int p0  = blockIdx.x << 7;
    int oc0 = blockIdx.y << 6;
    int b   = blockIdx.z;
    const float* xb = x + ((size_t)b << 20);
    int tid = threadIdx.x, tx = tid & 15, ty = tid >> 4;
    int tx4 = tx << 2, ty4 = ty << 2;
    float acc[8][8];
    #pragma unroll
    for (int a = 0; a < 8; ++a)
        #pragma unroll
        for (int b2 = 0; b2 < 8; ++b2) acc[a][b2] = 0.f;

    for (int cc0 = 0; cc0 < C_; cc0 += YKC) {
        __syncthreads();
        for (int e = tid; e < YKC * 128; e += 256) {
            int d = e >> 7, q = e & 127;
            af[d][q] = xb[(size_t)(cc0 + d) * N_ + p0 + q];
            int row = (q < 64) ? (cc0 + d) : (C_ + cc0 + d);
            wf[d][q] = Wt[(size_t)row * C_ + oc0 + (q & 63)];
        }
        __syncthreads();
        #pragma unroll 8
        for (int d = 0; d < YKC; ++d) {
            float4 a0 = *(const float4*)&af[d][ty4];
            float4 a1 = *(const float4*)&af[d][64 + ty4];
            float4 w0 = *(const float4*)&wf[d][tx4];
            float4 w1 = *(const float4*)&wf[d][64 + tx4];
            float pa[8] = {a0.x, a0.y, a0.z, a0.w, a1.x, a1.y, a1.z, a1.w};
            float wa[8] = {w0.x, w0.y, w0.z, w0.w, w1.x, w1.y, w1.z, w1.w};
            #pragma unroll
            for (int a = 0; a < 8; ++a)
                #pragma unroll
                for (int b2 = 0; b2 < 8; ++b2)
                    acc[a][b2] = fmaf(pa[a], wa[b2], acc[a][b2]);
        }
    }
    float4 bv = *(const float4*)&bias[oc0 + tx4];
    #pragma unroll
    for (int ha = 0; ha < 2; ++ha) {
        #pragma unroll
        for (int a = 0; a < 4; ++a) {
            int pg = (b << 12) + p0 + ha * 64 + ty4 + a;
            float4 o1, o2;
            o1.x = acc[ha * 4 + a][0]; o1.y = acc[ha * 4 + a][1];
            o1.z = acc[ha * 4 + a][2]; o1.w = acc[ha * 4 + a][3];
            o2.x = acc[ha * 4 + a][4] + bv.x; o2.y = acc[ha * 4 + a][5] + bv.y;
            o2.z = acc[ha * 4 + a][6] + bv.z; o2.w = acc[ha * 4 + a][7] + bv.w;
            *(float4*)&Y1[(size_t)pg * C_ + oc0 + tx4] = o1;
            *(float4*)&Y2[(size_t)pg * C_ + oc0 + tx4] = o2;
        }
    }
}

// ---------------- 9) weighted max epilogue ----------------
__global__ void final_kernel(const float* __restrict__ Y1, const float* __restrict__ Y2,
                             const int* __restrict__ nidx, const float* __restrict__ wgt,
                             float* __restrict__ out) {
    __shared__ int   snk[K_];
    __shared__ float swt[K_];
    int m = blockIdx.x;
    int c = threadIdx.x;
    if (c < K_) { snk[c] = nidx[m * K_ + c]; swt[c] = wgt[m * K_ + c]; }
    __syncthreads();
    float y2 = Y2[((size_t)m << 8) + c];
    float acc = -INF_F;
    #pragma unroll
    for (int k = 0; k < K_; ++k) {
        float v = swt[k] * (Y1[((size_t)snk[k] << 8) + c] + y2);
        acc = fmaxf(acc, v);
    }
    int b = m >> 12, i = m & 4095;
    out[(((size_t)b << 8) + c) * N_ + i] = acc;
}

extern "C" void kernel_launch(void* const* d_in, const int* in_sizes, int n_in,
                              void* d_out, int out_size, void* d_ws, size_t ws_size,
                              hipStream_t stream) {
    const float* x    = (const float*)d_in[0];
    const float* W    = (const float*)d_in[1];
    const float* bias = (const float*)d_in[2];
    float* out = (float*)d_out;

    float* ws = (float*)d_ws;
    size_t off = 0;
    float*  sq32 = ws + off;            off += 8192;
    double* sq64 = (double*)(ws + off); off += 16384;
    float*  Wt   = ws + off;            off += 131072;
    float*  wgt  = ws + off;            off += 131072;
    int*    nidx = (int*)(ws + off);    off += 131072;
    float*  Tq   = ws + off;            off += 8192;
    int*    cntg = (int*)(ws + off);    off += 8192;
    float*  tmin = ws + off;            off += 524288;     // 64 x 8192
    size_t svj_off = off;
    int*    svj  = (int*)(ws + off);    off += 1048576;    // 8192 x 128
    float*  xt   = ws + off;            off += 2097152;    // 2M floats
    size_t reuse0 = off;
    _Float16* xh = (_Float16*)(ws + reuse0);               // 2M halves
    // Y1/Y2 reuse svj+xt / xt-end+xh regions (dead after merge_rerank)
    float*  Y1   = ws + svj_off;
    float*  Y2   = Y1 + 2097152;

    hipMemsetAsync(cntg, 0, 8192 * sizeof(int), stream);
    sq_kernel<<<32, 256, 0, stream>>>(x, sq32, sq64);
    xt_kernel<<<dim3(64, 4, 2), 256, 0, stream>>>(x, xt, xh);
    wt_kernel<<<dim3(8, 4, 1), 256, 0, stream>>>(W, Wt);

    dist_kernel<<<dim3(32, 32, 2), 256, 0, stream>>>(xh, sq32, Tq, tmin, svj, cntg, 0);
    thresh_kernel<<<32, 256, 0, stream>>>(tmin, Tq);
    dist_kernel<<<dim3(32, 32, 2), 256, 0, stream>>>(xh, sq32, Tq, tmin, svj, cntg, 1);

    merge_rerank<<<256, 256, 0, stream>>>(svj, cntg, xt, sq64, nidx, wgt);
    y_kernel<<<dim3(32, 4, 2), 256, 0, stream>>>(x, Wt, bias, Y1, Y2);
    final_kernel<<<8192, 256, 0, stream>>>(Y1, Y2, nidx, wgt, out);
}

// Round 8
// 268.938 us; speedup vs baseline: 1.0651x; 1.0506x over previous
//
#include <hip/hip_runtime.h>

// NeighConv: B=2, C=256, N=4096, K=16
// Pipeline (V never materialized; Gram computed on upper triangle only):
//  1) sq_kernel:     sq32[p], sq64[p] = ||x_p||^2
//  2) xt_kernel:     xt[p][c] fp32 + xh[p][c] fp16 (point-major features)
//  3) wt_kernel:     Wt[d][c] = W[c][d]
//  4) dist mode0:    triangular MFMA gram; row-min AND transposed col-min
//  5) thresh:        T[q] = 20th smallest of 64 tile minima + 0.5 slack
//  6) dist mode1:    triangular gram again; dual-side filter-append survivors
//  7) merge_rerank:  fp64 re-rank of survivors -> true top-16 + cosine weights
//  8) y_kernel:      Y1[p]=feat@W1^T, Y2[p]=feat@W2^T + b
//  9) final_kernel:  out[b][c][i] = max_k w_k*(Y1[nk][c]+Y2[m][c])

#define B_ 2
#define C_ 256
#define N_ 4096
#define K_ 16
#define SCAP 128
#define INF_F 3.0e38f

typedef _Float16 f16x8 __attribute__((ext_vector_type(8)));
typedef float    f32x4 __attribute__((ext_vector_type(4)));

// async global->LDS, 16B per lane; LDS dest wave-uniform base + lane*16
#define GL16(gp, lp)                                                        \
    __builtin_amdgcn_global_load_lds(                                       \
        (const __attribute__((address_space(1))) void*)(gp),                \
        (__attribute__((address_space(3))) void*)(lp), 16, 0, 0)

// ---------------- 1) squared norms ----------------
__global__ void sq_kernel(const float* __restrict__ x,
                          float* __restrict__ sq32, double* __restrict__ sq64) {
    int p = blockIdx.x * 256 + threadIdx.x;           // 0..8191
    int b = p >> 12, i = p & 4095;
    const float* xb = x + ((size_t)b << 20) + i;
    double acc = 0.0;
    #pragma unroll 8
    for (int c = 0; c < C_; ++c) {
        double v = (double)xb[(size_t)c << 12];
        acc = fma(v, v, acc);
    }
    sq64[p] = acc;
    sq32[p] = (float)acc;
}

// ---------------- 2) transpose x -> xt fp32 + xh fp16 ----------------
__global__ void xt_kernel(const float* __restrict__ x, float* __restrict__ xt,
                          _Float16* __restrict__ xh) {
    __shared__ float tile[64][65];
    int i0 = blockIdx.x * 64;
    int c0 = blockIdx.y * 64;
    int b  = blockIdx.z;
    const float* xb = x + ((size_t)b << 20);
    int tid = threadIdx.x;
    int tx = tid & 63, tyy = tid >> 6;
    for (int r = tyy; r < 64; r += 4)
        tile[r][tx] = xb[(size_t)(c0 + r) * N_ + i0 + tx];
    __syncthreads();
    float*    xtb = xt + ((size_t)b << 20);
    _Float16* xhb = xh + ((size_t)b << 20);
    for (int r = tyy; r < 64; r += 4) {
        float v = tile[tx][r];
        xtb[(size_t)(i0 + r) * C_ + c0 + tx] = v;
        xhb[(size_t)(i0 + r) * C_ + c0 + tx] = (_Float16)v;
    }
}

// ---------------- 3) transpose W -> Wt[d][c] ----------------
__global__ void wt_kernel(const float* __restrict__ W, float* __restrict__ Wt) {
    __shared__ float tile[64][65];
    int d0 = blockIdx.x * 64;
    int c0 = blockIdx.y * 64;
    int tid = threadIdx.x;
    int tx = tid & 63, tyy = tid >> 6;
    for (int r = tyy; r < 64; r += 4)
        tile[r][tx] = W[(size_t)(c0 + r) * 512 + d0 + tx];
    __syncthreads();
    for (int r = tyy; r < 64; r += 4)
        Wt[(size_t)(d0 + r) * C_ + c0 + tx] = tile[tx][r];
}

// ---------------- 4/6) triangular LDS-staged MFMA distance kernel ----------------
// Only tiles jt >= it are computed (Gram symmetry); each block emits results
// for BOTH orientations (normal: queries = i-rows; transposed: queries = j-cols,
// value sq_i - 2*dot). Diagonal blocks emit normal only.
// block 256 = 4 waves (2x2 of 64x64), tile 128(i) x 128(j), BK=64 halfs.
// LDS XOR-swizzle (measured conflict-free): byte cb of row r at cb ^ ((r&7)<<4).
// gload_lds writes linearly -> inverse swizzle applied to global SOURCE addr.
__launch_bounds__(256, 2)
__global__ void dist_kernel(const _Float16* __restrict__ xh,
                            const float* __restrict__ sq32,
                            const float* __restrict__ Tq,
                            float* __restrict__ tmin,
                            int* __restrict__ svj, int* __restrict__ cntg,
                            int mode) {
    __shared__ _Float16 As[2][128][64];
    __shared__ _Float16 Bs[2][128][64];

    // decode triangular tile index: t -> (it, jt), jt >= it
    int t = blockIdx.x, b = blockIdx.y;
    int it = 0, off = 0;
    while (off + (32 - it) <= t) { off += 32 - it; ++it; }
    int jt = it + (t - off);

    int tid = threadIdx.x;
    int w = tid >> 6, l = tid & 63;
    int wr = w >> 1, wc = w & 1;
    int lr = l & 15, lg = l >> 4;
    const _Float16* xb = xh + ((size_t)b << 20);
    int rA0 = it * 128, rB0 = jt * 128;

    // staging geometry: lane l covers row l>>3 of its 8-row group, byte (l&7)*16
    int rsub = l >> 3;                          // 0..7
    int cb   = (l & 7) << 4;                    // 0..112 bytes

    auto STAGE = [&](int bf, int k0) {
        #pragma unroll
        for (int tt = 0; tt < 4; ++tt) {
            int rloc = w * 32 + tt * 8 + rsub;                 // 0..127
            int srch = (cb ^ ((rloc & 7) << 4)) >> 1;          // halfs
            GL16(xb + (size_t)(rA0 + rloc) * C_ + k0 + srch, &As[bf][w * 32 + tt * 8][0]);
            GL16(xb + (size_t)(rB0 + rloc) * C_ + k0 + srch, &Bs[bf][w * 32 + tt * 8][0]);
        }
    };

    f32x4 acc[4][4];
    #pragma unroll
    for (int mi = 0; mi < 4; ++mi)
        #pragma unroll
        for (int ni = 0; ni < 4; ++ni)
            acc[mi][ni] = (f32x4){0.f, 0.f, 0.f, 0.f};

    STAGE(0, 0);
    __syncthreads();                            // drains vmcnt -> buf0 ready
    #pragma unroll
    for (int kt = 0; kt < 4; ++kt) {
        int cur = kt & 1;
        if (kt < 3) STAGE(cur ^ 1, (kt + 1) * 64);
        #pragma unroll
        for (int kk = 0; kk < 2; ++kk) {
            int kh = kk * 32 + lg * 8;          // halfs offset within BK
            f16x8 af[4], bf4[4];
            #pragma unroll
            for (int mi = 0; mi < 4; ++mi) {
                int r = wr * 64 + mi * 16 + lr;
                af[mi] = *(const f16x8*)&As[cur][r][kh ^ ((r & 7) << 3)];
            }
            #pragma unroll
            for (int ni = 0; ni < 4; ++ni) {
                int r = wc * 64 + ni * 16 + lr;
                bf4[ni] = *(const f16x8*)&Bs[cur][r][kh ^ ((r & 7) << 3)];
            }
            #pragma unroll
            for (int mi = 0; mi < 4; ++mi)
                #pragma unroll
                for (int ni = 0; ni < 4; ++ni)
                    acc[mi][ni] = __builtin_amdgcn_mfma_f32_16x16x32_f16(
                        af[mi], bf4[ni], acc[mi][ni], 0, 0, 0);
        }
        __syncthreads();                        // buf[cur^1] staged; buf[cur] free
    }

    int bN = b << 12;
    int irow0 = it * 128 + wr * 64 + lg * 4;    // + mi*16 + r (this wave's rows)

    // scalars for both orientations
    float sj[4], si[4][4];
    #pragma unroll
    for (int ni = 0; ni < 4; ++ni)
        sj[ni] = sq32[bN + jt * 128 + wc * 64 + ni * 16 + lr];
    #pragma unroll
    for (int mi = 0; mi < 4; ++mi)
        #pragma unroll
        for (int r = 0; r < 4; ++r)
            si[mi][r] = sq32[bN + irow0 + mi * 16 + r];

    if (mode == 0) {
        // ---- normal: per-row min over this wave's 64 cols (value sq_j - 2dot)
        float rm[4][4];
        #pragma unroll
        for (int mi = 0; mi < 4; ++mi)
            #pragma unroll
            for (int r = 0; r < 4; ++r) rm[mi][r] = INF_F;
        #pragma unroll
        for (int ni = 0; ni < 4; ++ni)
            #pragma unroll
            for (int mi = 0; mi < 4; ++mi)
                #pragma unroll
                for (int r = 0; r < 4; ++r)
                    rm[mi][r] = fminf(rm[mi][r], sj[ni] - 2.0f * acc[mi][ni][r]);
        #pragma unroll
        for (int mask = 1; mask <= 8; mask <<= 1)
            #pragma unroll
            for (int mi = 0; mi < 4; ++mi)
                #pragma unroll
                for (int r = 0; r < 4; ++r)
                    rm[mi][r] = fminf(rm[mi][r], __shfl_xor(rm[mi][r], mask));
        if (lr == 0) {
            int tj = jt * 2 + wc;
            #pragma unroll
            for (int mi = 0; mi < 4; ++mi)
                #pragma unroll
                for (int r = 0; r < 4; ++r)
                    tmin[(size_t)tj * 8192 + bN + irow0 + mi * 16 + r] = rm[mi][r];
        }
        // ---- transposed: per-col min over this wave's 64 rows (value sq_i - 2dot)
        if (it != jt) {
            float tm[4];
            #pragma unroll
            for (int ni = 0; ni < 4; ++ni) {
                tm[ni] = INF_F;
                #pragma unroll
                for (int mi = 0; mi < 4; ++mi)
                    #pragma unroll
                    for (int r = 0; r < 4; ++r)
                        tm[ni] = fminf(tm[ni], si[mi][r] - 2.0f * acc[mi][ni][r]);
            }
            #pragma unroll
            for (int mask = 16; mask <= 32; mask <<= 1)
                #pragma unroll
                for (int ni = 0; ni < 4; ++ni)
                    tm[ni] = fminf(tm[ni], __shfl_xor(tm[ni], mask));
            if (lg == 0) {
                int tjp = it * 2 + wr;
                #pragma unroll
                for (int ni = 0; ni < 4; ++ni)
                    tmin[(size_t)tjp * 8192 + bN + jt * 128 + wc * 64 + ni * 16 + lr]
                        = tm[ni];
            }
        }
    } else {
        // ---- normal: append j-survivors for row-queries
        float tqr[4][4];
        #pragma unroll
        for (int mi = 0; mi < 4; ++mi)
            #pragma unroll
            for (int r = 0; r < 4; ++r)
                tqr[mi][r] = Tq[bN + irow0 + mi * 16 + r];
        #pragma unroll
        for (int ni = 0; ni < 4; ++ni) {
            int jg = jt * 128 + wc * 64 + ni * 16 + lr;
            #pragma unroll
            for (int mi = 0; mi < 4; ++mi)
                #pragma unroll
                for (int r = 0; r < 4; ++r) {
                    float v = sj[ni] - 2.0f * acc[mi][ni][r];
                    if (v <= tqr[mi][r]) {
                        int q = bN + irow0 + mi * 16 + r;
                        int pos = atomicAdd(&cntg[q], 1);
                        if (pos < SCAP) svj[(size_t)q * SCAP + pos] = jg;
                    }
                }
        }
        // ---- transposed: append i-survivors for col-queries
        if (it != jt) {
            float tqc[4];
            #pragma unroll
            for (int ni = 0; ni < 4; ++ni)
                tqc[ni] = Tq[bN + jt * 128 + wc * 64 + ni * 16 + lr];
            #pragma unroll
            for (int ni = 0; ni < 4; ++ni) {
                int q = bN + jt * 128 + wc * 64 + ni * 16 + lr;
                #pragma unroll
                for (int mi = 0; mi < 4; ++mi)
                    #pragma unroll
                    for (int r = 0; r < 4; ++r) {
                        float v = si[mi][r] - 2.0f * acc[mi][ni][r];
                        if (v <= tqc[ni]) {
                            int ig = irow0 + mi * 16 + r;      // batch-local
                            int pos = atomicAdd(&cntg[q], 1);
                            if (pos < SCAP) svj[(size_t)q * SCAP + pos] = ig;
                        }
                    }
            }
        }
    }
}

// ---------------- 5) per-query threshold = 20th smallest tile-min ----------------
__global__ void thresh_kernel(const float* __restrict__ tmin, float* __restrict__ Tq) {
    int q = blockIdx.x * 256 + threadIdx.x;           // 0..8191
    float sm[20];
    #pragma unroll
    for (int s = 0; s < 20; ++s) sm[s] = INF_F;
    for (int tj = 0; tj < 64; ++tj) {
        float v = tmin[(size_t)tj * 8192 + q];
        #pragma unroll
        for (int s = 0; s < 20; ++s) {                // branchless sorted insert
            bool lt = v < sm[s];
            float old = sm[s];
            sm[s] = lt ? v : sm[s];
            v = lt ? old : v;
        }
    }
    Tq[q] = sm[19] + 0.5f;
}

// ---------------- 7) fp64 re-rank of survivors + weights ----------------
__global__ void merge_rerank(const int* __restrict__ svj, const int* __restrict__ cntg,
                             const float* __restrict__ xt,
                             const double* __restrict__ sq64,
                             int* __restrict__ nidx, float* __restrict__ wgt) {
    __shared__ double d64[32][SCAP];
    int tid = threadIdx.x;
    int pl = tid >> 3, c8 = tid & 7;
    int m = (blockIdx.x << 5) + pl;
    int b = m >> 12;
    int cnt = cntg[m]; if (cnt > SCAP) cnt = SCAP;
    const float* rm = xt + ((size_t)m << 8);
    for (int cc = c8; cc < cnt; cc += 8) {
        int j = svj[(size_t)m * SCAP + cc];
        int n = (b << 12) + j;
        const float* rn = xt + ((size_t)n << 8);
        double acc = 0.0;
        #pragma unroll 8
        for (int c = 0; c < C_; c += 4) {
            float4 a4 = *(const float4*)(rm + c);
            float4 b4 = *(const float4*)(rn + c);
            acc = fma((double)a4.x, (double)b4.x, acc);
            acc = fma((double)a4.y, (double)b4.y, acc);
            acc = fma((double)a4.z, (double)b4.z, acc);
            acc = fma((double)a4.w, (double)b4.w, acc);
        }
        d64[pl][cc] = sq64[n] - 2.0 * acc;
    }
    __syncthreads();
    if (tid < 32) {
        int mm = (blockIdx.x << 5) + tid;
        int bb = mm >> 12;
        int cn = cntg[mm]; if (cn > SCAP) cn = SCAP;
        double td[K_]; int ti[K_];
        #pragma unroll
        for (int k = 0; k < K_; ++k) { td[k] = 1.0e300; ti[k] = 0; }
        for (int cc = 0; cc < cn; ++cc) {
            double d = d64[tid][cc];
            int j = svj[(size_t)mm * SCAP + cc];
            #pragma unroll
            for (int s = 0; s < K_; ++s) {            // sorted bubble-insert, strict <
                bool lt = d < td[s];
                double od = td[s]; int oi = ti[s];
                td[s] = lt ? d : od;  ti[s] = lt ? j : oi;
                d = lt ? od : d;      j = lt ? oi : j;
            }
        }
        double sqm = sq64[mm];
        double rdm = sqrt(sqm);
        #pragma unroll
        for (int k = 0; k < K_; ++k) {
            int n = (bb << 12) + ti[k];
            double sqn = sq64[n];
            double dot = 0.5 * (sqn - td[k]);
            double w = dot / (sqrt(sqn) * rdm);
            nidx[mm * K_ + k] = n;
            wgt[mm * K_ + k]  = (float)w;
        }
    }
}

// ---------------- 8) Y1 = feat@W1^T ; Y2 = feat@W2^T + b ----------------
#define YKC 32
__launch_bounds__(256, 2)
__global__ void y_kernel(const float* __restrict__ x, const float* __restrict__ Wt,
                         const float* __restrict__ bias,
                         float* __restrict__ Y1, float* __restrict__ Y2) {
    __shared__ float af[YKC][128];
    __shared__ float wf[YKC][128];
    int p0  = blockIdx.x << 7;
    int oc0 = blockIdx.y << 6;
    int b   = blockIdx.z;
    const float* xb = x + ((size_t)b << 20);
    int tid = threadIdx.x, tx = tid & 15, ty = tid >> 4;
    int tx4 = tx << 2, ty4 = ty << 2;
    float acc[8][8];
    #pragma unroll
    for (int a = 0; a < 8; ++a)
        #pragma unroll
        for (int b2 = 0; b2 < 8; ++b2) acc[a][b2] = 0.f;

    for (int cc0 = 0; cc0 < C_; cc0 += YKC) {
        __syncthreads();
        for (int e = tid; e < YKC * 128; e += 256) {
            int d = e >> 7, q = e & 127;
            af[d][q] = xb[(size_t)(cc0 + d) * N_ + p0 + q];
            int row = (q < 64) ? (cc0 + d) : (C_ + cc0 + d);
            wf[d][q] = Wt[(size_t)row * C_ + oc0 + (q & 63)];
        }
        __syncthreads();
        #pragma unroll 8
        for (int d = 0; d < YKC; ++d) {
            float4 a0 = *(const float4*)&af[d][ty4];
            float4 a1 = *(const float4*)&af[d][64 + ty4];
            float4 w0 = *(const float4*)&wf[d][tx4];
            float4 w1 = *(const float4*)&wf[d][64 + tx4];
            float pa[8] = {a0.x, a0.y, a0.z, a0.w, a1.x, a1.y, a1.z, a1.w};
            float wa[8] = {w0.x, w0.y, w0.z, w0.w, w1.x, w1.y, w1.z, w1.w};
            #pragma unroll
            for (int a = 0; a < 8; ++a)
                #pragma unroll
                for (int b2 = 0; b2 < 8; ++b2)
                    acc[a][b2] = fmaf(pa[a], wa[b2], acc[a][b2]);
        }
    }
    float4 bv = *(const float4*)&bias[oc0 + tx4];
    #pragma unroll
    for (int ha = 0; ha < 2; ++ha) {
        #pragma unroll
        for (int a = 0; a < 4; ++a) {
            int pg = (b << 12) + p0 + ha * 64 + ty4 + a;
            float4 o1, o2;
            o1.x = acc[ha * 4 + a][0]; o1.y = acc[ha * 4 + a][1];
            o1.z = acc[ha * 4 + a][2]; o1.w = acc[ha * 4 + a][3];
            o2.x = acc[ha * 4 + a][4] + bv.x; o2.y = acc[ha * 4 + a][5] + bv.y;
            o2.z = acc[ha * 4 + a][6] + bv.z; o2.w = acc[ha * 4 + a][7] + bv.w;
            *(float4*)&Y1[(size_t)pg * C_ + oc0 + tx4] = o1;
            *(float4*)&Y2[(size_t)pg * C_ + oc0 + tx4] = o2;
        }
    }
}

// ---------------- 9) weighted max epilogue ----------------
__global__ void final_kernel(const float* __restrict__ Y1, const float* __restrict__ Y2,
                             const int* __restrict__ nidx, const float* __restrict__ wgt,
                             float* __restrict__ out) {
    __shared__ int   snk[K_];
    __shared__ float swt[K_];
    int m = blockIdx.x;
    int c = threadIdx.x;
    if (c < K_) { snk[c] = nidx[m * K_ + c]; swt[c] = wgt[m * K_ + c]; }
    __syncthreads();
    float y2 = Y2[((size_t)m << 8) + c];
    float acc = -INF_F;
    #pragma unroll
    for (int k = 0; k < K_; ++k) {
        float v = swt[k] * (Y1[((size_t)snk[k] << 8) + c] + y2);
        acc = fmaxf(acc, v);
    }
    int b = m >> 12, i = m & 4095;
    out[(((size_t)b << 8) + c) * N_ + i] = acc;
}

extern "C" void kernel_launch(void* const* d_in, const int* in_sizes, int n_in,
                              void* d_out, int out_size, void* d_ws, size_t ws_size,
                              hipStream_t stream) {
    const float* x    = (const float*)d_in[0];
    const float* W    = (const float*)d_in[1];
    const float* bias = (const float*)d_in[2];
    float* out = (float*)d_out;

    float* ws = (float*)d_ws;
    size_t off = 0;
    float*  sq32 = ws + off;            off += 8192;
    double* sq64 = (double*)(ws + off); off += 16384;
    float*  Wt   = ws + off;            off += 131072;
    float*  wgt  = ws + off;            off += 131072;
    int*    nidx = (int*)(ws + off);    off += 131072;
    float*  Tq   = ws + off;            off += 8192;
    int*    cntg = (int*)(ws + off);    off += 8192;
    float*  tmin = ws + off;            off += 524288;     // 64 x 8192
    size_t svj_off = off;
    int*    svj  = (int*)(ws + off);    off += 1048576;    // 8192 x 128
    float*  xt   = ws + off;            off += 2097152;    // 2M floats
    size_t reuse0 = off;
    _Float16* xh = (_Float16*)(ws + reuse0);               // 2M halves
    // Y1/Y2 reuse svj+xt / xt-end+xh regions (dead after merge_rerank)
    float*  Y1   = ws + svj_off;
    float*  Y2   = Y1 + 2097152;

    hipMemsetAsync(cntg, 0, 8192 * sizeof(int), stream);
    sq_kernel<<<32, 256, 0, stream>>>(x, sq32, sq64);
    xt_kernel<<<dim3(64, 4, 2), 256, 0, stream>>>(x, xt, xh);
    wt_kernel<<<dim3(8, 4, 1), 256, 0, stream>>>(W, Wt);

    dist_kernel<<<dim3(528, 2, 1), 256, 0, stream>>>(xh, sq32, Tq, tmin, svj, cntg, 0);
    thresh_kernel<<<32, 256, 0, stream>>>(tmin, Tq);
    dist_kernel<<<dim3(528, 2, 1), 256, 0, stream>>>(xh, sq32, Tq, tmin, svj, cntg, 1);

    merge_rerank<<<256, 256, 0, stream>>>(svj, cntg, xt, sq64, nidx, wgt);
    y_kernel<<<dim3(32, 4, 2), 256, 0, stream>>>(x, Wt, bias, Y1, Y2);
    final_kernel<<<8192, 256, 0, stream>>>(Y1, Y2, nidx, wgt, out);
}